// Round 8
// baseline (6132.235 us; speedup 1.0000x reference)
//
#include <hip/hip_runtime.h>

typedef short bf16x8 __attribute__((ext_vector_type(8)));
typedef float f32x4 __attribute__((ext_vector_type(4)));

#define B_ 256
#define T_ 1024
#define H_ 512
#define E_ 256
#define O_ 256
#define V_ 256

// Prepped operands in device globals: graph-safe, rewritten every launch.
__device__ __align__(16) unsigned g_P2[V_ * 256];         // P packed: slot v*256+pp*16+lo = (P[pp*32+lo], P[pp*32+16+lo])
__device__ __align__(16) unsigned short g_Whf[H_ * H_];   // Wh in MFMA B-frag layout (512 KB)
__device__ __align__(16) unsigned short g_Wdf[O_ * H_];   // Wd in MFMA B-frag layout (256 KB)

// Cross-block h exchange: ROW-MAJOR packed-u32 bf16 pairs (cols 2m,2m+1), so the
// byte layout is exactly the MFMA A-fragment layout -> frags load straight from L3.
__device__ __align__(16) unsigned g_ex[2][16][16 * 256];  // 2 x 16 groups x (16 rows x 256 u32) = 512 KB
__device__ unsigned g_flag[16][64];                       // flags [g][0..3], 256B-padded per group

__device__ __forceinline__ unsigned short f2bf(float f) {
    union { float f; unsigned int u; } v; v.f = f;
    unsigned int r = v.u + 0x7fffu + ((v.u >> 16) & 1u);   // RNE
    return (unsigned short)(r >> 16);
}
__device__ __forceinline__ float bf2f(unsigned short s) {
    union { unsigned int u; float f; } v; v.u = ((unsigned int)s) << 16;
    return v.f;
}
#define TANH_(v_) (1.f - __fdividef(2.f, __expf((v_) + (v_)) + 1.f))

// ---------------- K1a: P2 = packed(b + emb @ Wx^T); zero flags ----------------
__global__ void k_embWx(const float* __restrict__ emb, const float* __restrict__ W,
                        const float* __restrict__ bb) {
    if (blockIdx.x == 0)
        for (int i = threadIdx.x; i < 16 * 64; i += 256) ((unsigned*)g_flag)[i] = 0;
    __shared__ float e[E_];
    int v = blockIdx.x;
    e[threadIdx.x] = emb[(size_t)v * E_ + threadIdx.x];
    __syncthreads();
#pragma unroll
    for (int rep = 0; rep < 2; rep++) {
        int n = threadIdx.x + rep * 256;
        const float4* wr4 = (const float4*)(W + (size_t)n * (E_ + H_));
        float s = bb[n];
        for (int k = 0; k < E_ / 4; k++) {
            float4 wv = wr4[k];
            s += e[4*k] * wv.x + e[4*k+1] * wv.y + e[4*k+2] * wv.z + e[4*k+3] * wv.w;
        }
        int pp = n >> 5, half = (n >> 4) & 1, lo = n & 15;
        ((unsigned short*)g_P2)[(v * 256 + pp * 16 + lo) * 2 + half] = f2bf(s);
    }
}

// ---------------- K1b/K1c: weight -> MFMA B-fragment layout (bf16) ----------------
__global__ void k_fragWh(const float* __restrict__ W) {
    int gid = blockIdx.x * blockDim.x + threadIdx.x;
    int l = gid & 63, tile = gid >> 6;
    int kt = tile & 15, nt = tile >> 4;
    int n = nt * 16 + (l & 15), k0 = kt * 32 + (l >> 4) * 8;
    const float* src = W + (size_t)n * (E_ + H_) + E_ + k0;
#pragma unroll
    for (int j = 0; j < 8; j++) g_Whf[(size_t)gid * 8 + j] = f2bf(src[j]);
}
__global__ void k_fragWd(const float* __restrict__ Wd) {
    int gid = blockIdx.x * blockDim.x + threadIdx.x;
    int l = gid & 63, tile = gid >> 6;
    int kt = tile & 15, nt = tile >> 4;
    int n = nt * 16 + (l & 15), k0 = kt * 32 + (l >> 4) * 8;
    const float* src = Wd + (size_t)n * H_ + k0;
#pragma unroll
    for (int j = 0; j < 8; j++) g_Wdf[(size_t)gid * 8 + j] = f2bf(src[j]);
}

// Exchange store: pack (col 2m, 2m+1) via one shfl_xor; even lane stores rows 0,1 of
// its hi-group, odd lane rows 2,3 (4 u32 agent stores/lane = 8 store instrs/wave).
#define EXST(J_, RG_, MV_) do {                                                        \
    unsigned nb_ = ((unsigned)__shfl_xor((int)(MV_), 1)) & 0xffffu;                    \
    unsigned pk_ = (lo & 1) ? (nb_ | ((unsigned)(MV_) << 16))                          \
                            : ((unsigned)(MV_) | (nb_ << 16));                         \
    if (((lo & 1) == 0) == ((RG_) < 2))                                                \
        __hip_atomic_store(exw + (hi * 4 + (RG_)) * 256 + (nt0 + (J_)) * 8 + (lo >> 1),\
                           pk_, __ATOMIC_RELAXED, __HIP_MEMORY_SCOPE_AGENT);           \
} while (0)

// ---------------- K2: recurrence — zero LDS, frags direct from L3 ----------------
// 64 blocks = 16 groups x 4 quarters; 256 thr = 4 waves; wave owns ntiles {q*8+2w, +1}.
// breg 2x16 frags = 128 VGPRs pinned (grant = 65536/block-threads: 256thr -> 256).
// Per step: spin(1 flag line) -> 32 u64 agent frag loads (one L3 RT, pipelined) ->
// 32 MFMA -> tanh -> ex stores -> hs stores -> vmcnt(8) [ex done, hs FLY - R7's
// vmcnt(0) hs-drain was on the chain] -> s_barrier -> flag STORE (no RMW, one RT
// cheaper than R7's add+poll). Parity reuse safe: flag t implies partner's step-t-1
// frag reads (issued before its ex stores, covered by its vmcnt(8)) completed.
__global__ void __launch_bounds__(256) k_rnn(const int* __restrict__ x,
                                             const float* __restrict__ h0,
                                             float* __restrict__ out) {
    const int tid = threadIdx.x;
    const int w = tid >> 6, l = tid & 63;
    const int hi = l >> 4, lo = l & 15;
    const int g = blockIdx.x >> 2, q = blockIdx.x & 3;
    const int r0 = g * 16;
    const int nt0 = q * 8 + 2 * w;              // even global ntile; owns nt0, nt0+1
    const int n0 = nt0 * 16 + lo;
    const int pp = q * 4 + w;                   // packed-P pair index

    // pinned Wh B-frags (2 x 16 x 4 = 128 VGPRs)
    bf16x8 breg[2][16];
#pragma unroll
    for (int j = 0; j < 2; j++)
#pragma unroll
        for (int kt = 0; kt < 16; kt++)
            breg[j][kt] = *(const bf16x8*)(g_Whf + ((nt0 + j) * 16 + kt) * 512 + l * 8);

    // stage h0 -> g_ex[0][g]: all 4 blocks write identical data (benign) so t=0
    // needs no cross-block sync; own vmcnt(0)+barrier makes own L3 copy visible.
    {
        unsigned* ex0 = &g_ex[0][g][0];
#pragma unroll 1
        for (int k = 0; k < 16; k++) {
            const float* hp = h0 + (size_t)(r0 + k) * H_ + tid * 2;
            unsigned pk = (unsigned)f2bf(hp[0]) | ((unsigned)f2bf(hp[1]) << 16);
            __hip_atomic_store(ex0 + k * 256 + tid, pk, __ATOMIC_RELAXED, __HIP_MEMORY_SCOPE_AGENT);
        }
    }
    asm volatile("s_waitcnt vmcnt(0)" ::: "memory");
    __syncthreads();

    const int xr = r0 + hi * 4;                 // thread's 4 batch rows xr..xr+3
    int xn0 = x[(xr + 0) * T_], xn1 = x[(xr + 1) * T_],
        xn2 = x[(xr + 2) * T_], xn3 = x[(xr + 3) * T_];
    unsigned u0 = g_P2[xn0 * 256 + pp * 16 + lo];
    unsigned u1 = g_P2[xn1 * 256 + pp * 16 + lo];
    unsigned u2 = g_P2[xn2 * 256 + pp * 16 + lo];
    unsigned u3 = g_P2[xn3 * 256 + pp * 16 + lo];

    const int eo0 = (xr + 0) * (T_ * H_) + n0;
    const int eo1 = (xr + 1) * (T_ * H_) + n0;
    const int eo2 = (xr + 2) * (T_ * H_) + n0;
    const int eo3 = (xr + 3) * (T_ * H_) + n0;

    unsigned short* hs = (unsigned short*)out;   // hs bf16 in-place in d_out
    const unsigned long long* flq = (const unsigned long long*)&g_flag[g][0];
    unsigned short m00 = 0, m01 = 0, m02 = 0, m03 = 0, m10 = 0, m11 = 0, m12 = 0, m13 = 0;

#pragma unroll 1
    for (unsigned t = 0; t < T_; t++) {
        // wait for h(t): all 4 flags >= t (plain-store flags, one 16-B line)
        if (t) {
            for (;;) {
                unsigned long long f0 = __hip_atomic_load(flq,     __ATOMIC_RELAXED, __HIP_MEMORY_SCOPE_AGENT);
                unsigned long long f1 = __hip_atomic_load(flq + 1, __ATOMIC_RELAXED, __HIP_MEMORY_SCOPE_AGENT);
                unsigned a = (unsigned)f0, b = (unsigned)(f0 >> 32);
                unsigned c = (unsigned)f1, d = (unsigned)(f1 >> 32);
                unsigned m = a < b ? a : b, m2 = c < d ? c : d;
                if ((m < m2 ? m : m2) >= t) break;
                __builtin_amdgcn_s_sleep(1);
            }
        }
        __builtin_amdgcn_sched_barrier(0);

        // A-frags direct from L3: row lo, cols kt*32+hi*8..+7 (two u64 agent loads each)
        const unsigned long long* exq =
            (const unsigned long long*)&g_ex[t & 1][g][0] + lo * 128 + hi * 2;
        bf16x8 fr[16];
#pragma unroll
        for (int kt = 0; kt < 16; kt++) {
            unsigned long long q0 = __hip_atomic_load(exq + kt * 8,     __ATOMIC_RELAXED, __HIP_MEMORY_SCOPE_AGENT);
            unsigned long long q1 = __hip_atomic_load(exq + kt * 8 + 1, __ATOMIC_RELAXED, __HIP_MEMORY_SCOPE_AGENT);
            union { unsigned long long qq[2]; bf16x8 v; } uu;
            uu.qq[0] = q0; uu.qq[1] = q1;
            fr[kt] = uu.v;
        }
        // x(t+1) prefetch
        const int tn = (t < T_ - 1) ? (int)(t + 1) : (int)t;
        xn0 = x[(xr + 0) * T_ + tn]; xn1 = x[(xr + 1) * T_ + tn];
        xn2 = x[(xr + 2) * T_ + tn]; xn3 = x[(xr + 3) * T_ + tn];
        __builtin_amdgcn_sched_barrier(0);   // keep all loads issued before MFMA block

        // MFMA: 2 chains (one per ntile), C-init carries u(t)
        f32x4 accA = {bf2f((unsigned short)u0), bf2f((unsigned short)u1),
                      bf2f((unsigned short)u2), bf2f((unsigned short)u3)};
        f32x4 accB = {bf2f((unsigned short)(u0 >> 16)), bf2f((unsigned short)(u1 >> 16)),
                      bf2f((unsigned short)(u2 >> 16)), bf2f((unsigned short)(u3 >> 16))};
#pragma unroll
        for (int kt = 0; kt < 16; kt++) {
            accA = __builtin_amdgcn_mfma_f32_16x16x32_bf16(fr[kt], breg[0][kt], accA, 0, 0, 0);
            accB = __builtin_amdgcn_mfma_f32_16x16x32_bf16(fr[kt], breg[1][kt], accB, 0, 0, 0);
        }

        // u(t+1) (L2-resident; hides under epilogue+sync)
        u0 = g_P2[xn0 * 256 + pp * 16 + lo];
        u1 = g_P2[xn1 * 256 + pp * 16 + lo];
        u2 = g_P2[xn2 * 256 + pp * 16 + lo];
        u3 = g_P2[xn3 * 256 + pp * 16 + lo];

        // tanh -> bf16
        m00 = f2bf(TANH_(accA[0])); m01 = f2bf(TANH_(accA[1]));
        m02 = f2bf(TANH_(accA[2])); m03 = f2bf(TANH_(accA[3]));
        m10 = f2bf(TANH_(accB[0])); m11 = f2bf(TANH_(accB[1]));
        m12 = f2bf(TANH_(accB[2])); m13 = f2bf(TANH_(accB[3]));

        // exchange stores FIRST (8 instrs/wave), then hs stores (8, never drained)
        unsigned* exw = &g_ex[(t + 1) & 1][g][0];
        __builtin_amdgcn_sched_barrier(0);
        EXST(0, 0, m00); EXST(0, 1, m01); EXST(0, 2, m02); EXST(0, 3, m03);
        EXST(1, 0, m10); EXST(1, 1, m11); EXST(1, 2, m12); EXST(1, 3, m13);
        __builtin_amdgcn_sched_barrier(0);
        const int tb = (int)t << 9;
        hs[eo0 + tb] = m00; hs[eo1 + tb] = m01; hs[eo2 + tb] = m02; hs[eo3 + tb] = m03;
        hs[eo0 + tb + 16] = m10; hs[eo1 + tb + 16] = m11;
        hs[eo2 + tb + 16] = m12; hs[eo3 + tb + 16] = m13;
        __builtin_amdgcn_sched_barrier(0);
        // counted wait: last 8 vmem ops are the hs stores -> ex stores complete, hs fly
        asm volatile("s_waitcnt vmcnt(8)" ::: "memory");
        __builtin_amdgcn_s_barrier();
        if (tid == 0)
            __hip_atomic_store(&g_flag[g][q], t + 1, __ATOMIC_RELAXED, __HIP_MEMORY_SCOPE_AGENT);
    }

    // h_final (fp32) from the last step's register values
    float* hfin = out + (size_t)B_ * T_ * O_;
    hfin[(xr + 0) * H_ + n0] = bf2f(m00);
    hfin[(xr + 1) * H_ + n0] = bf2f(m01);
    hfin[(xr + 2) * H_ + n0] = bf2f(m02);
    hfin[(xr + 3) * H_ + n0] = bf2f(m03);
    hfin[(xr + 0) * H_ + n0 + 16] = bf2f(m10);
    hfin[(xr + 1) * H_ + n0 + 16] = bf2f(m11);
    hfin[(xr + 2) * H_ + n0 + 16] = bf2f(m12);
    hfin[(xr + 3) * H_ + n0 + 16] = bf2f(m13);
}

// ---------------- K3: outputs = hs @ Wd^T + bd, in-place over hs slots ----------------
__launch_bounds__(512, 2)
__global__ void k_out(const float* __restrict__ bd, float* out) {
    int tid = threadIdx.x;
    int w = tid >> 6, l = tid & 63;
    int hi = l >> 4, lo = l & 15;
    size_t m0 = (size_t)blockIdx.x * 256 + w * 32;
    const unsigned short* hsb = (const unsigned short*)out;
    float bdv[16];
#pragma unroll
    for (int nt = 0; nt < 16; nt++) bdv[nt] = bd[nt * 16 + lo];
    f32x4 acc[2][16];
#pragma unroll
    for (int m = 0; m < 2; m++)
#pragma unroll
        for (int nt = 0; nt < 16; nt++) { acc[m][nt][0] = 0.f; acc[m][nt][1] = 0.f; acc[m][nt][2] = 0.f; acc[m][nt][3] = 0.f; }
#pragma unroll 2
    for (int kt = 0; kt < 16; kt++) {
        bf16x8 a0 = *(const bf16x8*)(hsb + (m0 + lo) * 512 + kt * 32 + hi * 8);
        bf16x8 a1 = *(const bf16x8*)(hsb + (m0 + 16 + lo) * 512 + kt * 32 + hi * 8);
#pragma unroll
        for (int nt = 0; nt < 16; nt++) {
            bf16x8 bf = *(const bf16x8*)(g_Wdf + (size_t)(nt * 16 + kt) * 512 + l * 8);
            acc[0][nt] = __builtin_amdgcn_mfma_f32_16x16x32_bf16(a0, bf, acc[0][nt], 0, 0, 0);
            acc[1][nt] = __builtin_amdgcn_mfma_f32_16x16x32_bf16(a1, bf, acc[1][nt], 0, 0, 0);
        }
    }
#pragma unroll
    for (int m = 0; m < 2; m++)
#pragma unroll
        for (int nt = 0; nt < 16; nt++)
#pragma unroll
            for (int rg = 0; rg < 4; rg++) {
                size_t row = m0 + m * 16 + hi * 4 + rg;
                out[row * O_ + nt * 16 + lo] = acc[m][nt][rg] + bdv[nt];
            }
}

extern "C" void kernel_launch(void* const* d_in, const int* in_sizes, int n_in,
                              void* d_out, int out_size, void* d_ws, size_t ws_size,
                              hipStream_t stream) {
    const int*   x   = (const int*)d_in[0];
    const float* h0  = (const float*)d_in[1];
    const float* emb = (const float*)d_in[2];
    const float* W   = (const float*)d_in[3];
    const float* b   = (const float*)d_in[4];
    const float* Wd  = (const float*)d_in[5];
    const float* bd  = (const float*)d_in[6];
    float* out = (float*)d_out;

    k_embWx<<<dim3(V_), dim3(256), 0, stream>>>(emb, W, b);
    k_fragWh<<<dim3(128), dim3(256), 0, stream>>>(W);
    k_fragWd<<<dim3(64), dim3(256), 0, stream>>>(Wd);
    k_rnn<<<dim3(64), dim3(256), 0, stream>>>(x, h0, out);
    k_out<<<dim3(1024), dim3(512), 0, stream>>>(bd, out);
}

// Round 9
// 3838.927 us; speedup vs baseline: 1.5974x; 1.5974x over previous
//
#include <hip/hip_runtime.h>

typedef short bf16x8 __attribute__((ext_vector_type(8)));
typedef float f32x4 __attribute__((ext_vector_type(4)));

#define B_ 256
#define T_ 1024
#define H_ 512
#define E_ 256
#define O_ 256
#define V_ 256

// Prepped operands in device globals: graph-safe, rewritten every launch.
__device__ __align__(16) unsigned short g_P[V_ * H_];     // P = emb@Wx^T + b, bf16 (256 KB)
__device__ __align__(16) unsigned short g_Whf[H_ * H_];   // Wh in MFMA B-frag layout (512 KB)
__device__ __align__(16) unsigned short g_Wdf[O_ * H_];   // Wd in MFMA B-frag layout (256 KB)

// Cross-block h exchange: ROW-MAJOR packed-u32 bf16 pairs — byte image == the
// row-major bf16 h matrix, which is exactly what the swizzled LDS copy + MFMA
// A-frag reads consume. Parity double-buffered.
__device__ __align__(16) unsigned g_ex[2][16][16 * 256];  // 2 x 16 groups x 16 KB
__device__ unsigned g_flag[16][64];                       // flags [g][0..3], 256B/group

__device__ __forceinline__ unsigned short f2bf(float f) {
    union { float f; unsigned int u; } v; v.f = f;
    unsigned int r = v.u + 0x7fffu + ((v.u >> 16) & 1u);   // RNE
    return (unsigned short)(r >> 16);
}
__device__ __forceinline__ float bf2f(unsigned short s) {
    union { unsigned int u; float f; } v; v.u = ((unsigned int)s) << 16;
    return v.f;
}
#define TANH_(v_) (1.f - __fdividef(2.f, __expf((v_) + (v_)) + 1.f))

// ---------------- K1a: P = b + emb @ Wx^T (bf16); zero flags ----------------
__global__ void k_embWx(const float* __restrict__ emb, const float* __restrict__ W,
                        const float* __restrict__ bb) {
    if (blockIdx.x == 0)
        for (int i = threadIdx.x; i < 16 * 64; i += 256) ((unsigned*)g_flag)[i] = 0;
    __shared__ float e[E_];
    int v = blockIdx.x;
    e[threadIdx.x] = emb[(size_t)v * E_ + threadIdx.x];
    __syncthreads();
#pragma unroll
    for (int rep = 0; rep < 2; rep++) {
        int n = threadIdx.x + rep * 256;
        const float4* wr4 = (const float4*)(W + (size_t)n * (E_ + H_));
        float s = bb[n];
        for (int k = 0; k < E_ / 4; k++) {
            float4 wv = wr4[k];
            s += e[4*k] * wv.x + e[4*k+1] * wv.y + e[4*k+2] * wv.z + e[4*k+3] * wv.w;
        }
        g_P[v * H_ + n] = f2bf(s);
    }
}

// ---------------- K1b/K1c: weight -> MFMA B-fragment layout (bf16) ----------------
__global__ void k_fragWh(const float* __restrict__ W) {
    int gid = blockIdx.x * blockDim.x + threadIdx.x;
    int l = gid & 63, tile = gid >> 6;
    int kt = tile & 15, nt = tile >> 4;
    int n = nt * 16 + (l & 15), k0 = kt * 32 + (l >> 4) * 8;
    const float* src = W + (size_t)n * (E_ + H_) + E_ + k0;
#pragma unroll
    for (int j = 0; j < 8; j++) g_Whf[(size_t)gid * 8 + j] = f2bf(src[j]);
}
__global__ void k_fragWd(const float* __restrict__ Wd) {
    int gid = blockIdx.x * blockDim.x + threadIdx.x;
    int l = gid & 63, tile = gid >> 6;
    int kt = tile & 15, nt = tile >> 4;
    int n = nt * 16 + (l & 15), k0 = kt * 32 + (l >> 4) * 8;
    const float* src = Wd + (size_t)n * H_ + k0;
#pragma unroll
    for (int j = 0; j < 8; j++) g_Wdf[(size_t)gid * 8 + j] = f2bf(src[j]);
}

// ---------------- K2: recurrence — R7 geometry + R8 protocol, vectorized gather ----------------
// 64 blocks = 16 groups x 4 quarters; 512 thr = 8 waves; wave owns ntile q*8+w
// (breg = 16 frags = 64 VGPRs; total ~100 < the empirical hard 128-reg ceiling,
// R1-R8). Per step: MFMA (A from swizzled LDS) -> tanh -> EX atomic stores ->
// u prefetch -> vmcnt(4) [ex retired, u flies] -> barrier -> flag PLAIN store ->
// poll one 16-B flag line -> gather 4xu64 + 2x ds_write_b128 (R7 did 16 scalar
// b16 writes here) -> barrier -> hs stores dead-LAST (retire during next step;
// never on the chain). Final step skips the whole sync.
__global__ void __launch_bounds__(512) k_rnn(const int* __restrict__ x,
                                             const float* __restrict__ h0,
                                             float* __restrict__ out) {
    __shared__ __align__(16) unsigned short lds_h[16 * 512];   // 16 KB packed image
    const int tid = threadIdx.x;
    const int w = tid >> 6, l = tid & 63;
    const int hi = l >> 4, lo = l & 15;
    const int g = blockIdx.x >> 2, q = blockIdx.x & 3;
    const int r0 = g * 16;
    const int nt = q * 8 + w;
    const int n = nt * 16 + lo;
    const int sw = (lo & 7) << 4;               // A-read swizzle

    // pinned Wh B-frags: 16 x 4 = 64 VGPRs
    bf16x8 breg[16];
#pragma unroll
    for (int kt = 0; kt < 16; kt++)
        breg[kt] = *(const bf16x8*)(g_Whf + (nt * 16 + kt) * 512 + l * 8);

    // stage h0 -> LDS packed image (swizzled): thread = (row, 32-byte chunk)
    {
        const int row = tid >> 5;
        const int cb = (tid & 31) * 32;          // byte offset in row (u32-pair granular)
        const float* hp = h0 + (size_t)(r0 + row) * H_ + (tid & 31) * 16;
        unsigned pk[8];
#pragma unroll
        for (int i = 0; i < 8; i++)
            pk[i] = (unsigned)f2bf(hp[2 * i]) | ((unsigned)f2bf(hp[2 * i + 1]) << 16);
        char* hw = (char*)lds_h + row * 1024;
        const int gsw = (row & 7) << 4;
        *(uint4*)(hw + ((cb)      ^ gsw)) = make_uint4(pk[0], pk[1], pk[2], pk[3]);
        *(uint4*)(hw + ((cb + 16) ^ gsw)) = make_uint4(pk[4], pk[5], pk[6], pk[7]);
    }
    __syncthreads();

    const int xr = r0 + hi * 4;                 // thread's 4 batch rows
    unsigned u0 = g_P[x[(xr + 0) * T_] * H_ + n];
    unsigned u1 = g_P[x[(xr + 1) * T_] * H_ + n];
    unsigned u2 = g_P[x[(xr + 2) * T_] * H_ + n];
    unsigned u3 = g_P[x[(xr + 3) * T_] * H_ + n];

    const int eo0 = (xr + 0) * (T_ * H_) + n;
    const int eo1 = (xr + 1) * (T_ * H_) + n;
    const int eo2 = (xr + 2) * (T_ * H_) + n;
    const int eo3 = (xr + 3) * (T_ * H_) + n;

    unsigned short* hs = (unsigned short*)out;   // hs bf16 in-place in d_out
    const unsigned long long* flq = (const unsigned long long*)&g_flag[g][0];
    unsigned m00 = 0, m01 = 0, m02 = 0, m03 = 0;

#pragma unroll 1
    for (unsigned t = 0; t < T_; t++) {
        // x(t+1) early (L2 latency hides under MFMA)
        const int tn = (t < T_ - 1) ? (int)(t + 1) : (int)t;
        const int xn0 = x[(xr + 0) * T_ + tn], xn1 = x[(xr + 1) * T_ + tn];
        const int xn2 = x[(xr + 2) * T_ + tn], xn3 = x[(xr + 3) * T_ + tn];

        // MFMA: acc = h @ Wh^T (+u via C-init), 2 chains (even/odd kt)
        f32x4 aca = {bf2f((unsigned short)u0), bf2f((unsigned short)u1),
                     bf2f((unsigned short)u2), bf2f((unsigned short)u3)};
        f32x4 acb = {0.f, 0.f, 0.f, 0.f};
        const char* hb = (const char*)lds_h;
#pragma unroll
        for (int kt = 0; kt < 16; kt += 2) {
            bf16x8 a0 = *(const bf16x8*)(hb + lo * 1024 + ((kt * 64 + hi * 16) ^ sw));
            bf16x8 a1 = *(const bf16x8*)(hb + lo * 1024 + (((kt + 1) * 64 + hi * 16) ^ sw));
            aca = __builtin_amdgcn_mfma_f32_16x16x32_bf16(a0, breg[kt],     aca, 0, 0, 0);
            acb = __builtin_amdgcn_mfma_f32_16x16x32_bf16(a1, breg[kt + 1], acb, 0, 0, 0);
        }

        // tanh -> bf16
        m00 = f2bf(TANH_(aca[0] + acb[0]));
        m01 = f2bf(TANH_(aca[1] + acb[1]));
        m02 = f2bf(TANH_(aca[2] + acb[2]));
        m03 = f2bf(TANH_(aca[3] + acb[3]));

        if (t < T_ - 1) {
            // pack col pairs (uniform shfls), EX atomic stores (2/lane, predicated)
            unsigned pk0, pk1, pk2, pk3;
            {
                unsigned b0 = ((unsigned)__shfl_xor((int)m00, 1)) & 0xffffu;
                unsigned b1 = ((unsigned)__shfl_xor((int)m01, 1)) & 0xffffu;
                unsigned b2 = ((unsigned)__shfl_xor((int)m02, 1)) & 0xffffu;
                unsigned b3 = ((unsigned)__shfl_xor((int)m03, 1)) & 0xffffu;
                if (lo & 1) { pk0 = b0 | (m00 << 16); pk1 = b1 | (m01 << 16);
                              pk2 = b2 | (m02 << 16); pk3 = b3 | (m03 << 16); }
                else        { pk0 = m00 | (b0 << 16); pk1 = m01 | (b1 << 16);
                              pk2 = m02 | (b2 << 16); pk3 = m03 | (b3 << 16); }
            }
            unsigned* exw = &g_ex[(t + 1) & 1][g][0] + (n >> 1);
            __builtin_amdgcn_sched_barrier(0);
            if (!(lo & 1)) {
                __hip_atomic_store(exw + (hi * 4 + 0) * 256, pk0, __ATOMIC_RELAXED, __HIP_MEMORY_SCOPE_AGENT);
                __hip_atomic_store(exw + (hi * 4 + 1) * 256, pk1, __ATOMIC_RELAXED, __HIP_MEMORY_SCOPE_AGENT);
            } else {
                __hip_atomic_store(exw + (hi * 4 + 2) * 256, pk2, __ATOMIC_RELAXED, __HIP_MEMORY_SCOPE_AGENT);
                __hip_atomic_store(exw + (hi * 4 + 3) * 256, pk3, __ATOMIC_RELAXED, __HIP_MEMORY_SCOPE_AGENT);
            }
            // u(t+1) prefetch AFTER ex stores (so vmcnt(4) retires ex, leaves u flying)
            u0 = g_P[xn0 * H_ + n];
            u1 = g_P[xn1 * H_ + n];
            u2 = g_P[xn2 * H_ + n];
            u3 = g_P[xn3 * H_ + n];
            __builtin_amdgcn_sched_barrier(0);
            asm volatile("s_waitcnt vmcnt(4)" ::: "memory");   // ex retired; u flies
            __builtin_amdgcn_s_barrier();
            if (tid == 0)
                __hip_atomic_store(&g_flag[g][q], t + 1, __ATOMIC_RELAXED, __HIP_MEMORY_SCOPE_AGENT);

            // poll: all 4 quarters posted step t (one 16-B line)
            for (;;) {
                unsigned long long f0 = __hip_atomic_load(flq,     __ATOMIC_RELAXED, __HIP_MEMORY_SCOPE_AGENT);
                unsigned long long f1 = __hip_atomic_load(flq + 1, __ATOMIC_RELAXED, __HIP_MEMORY_SCOPE_AGENT);
                unsigned a = (unsigned)f0, b = (unsigned)(f0 >> 32);
                unsigned c = (unsigned)f1, d = (unsigned)(f1 >> 32);
                unsigned m = a < b ? a : b, m2 = c < d ? c : d;
                if ((m < m2 ? m : m2) > t) break;
                __builtin_amdgcn_s_sleep(1);
            }
            __builtin_amdgcn_sched_barrier(0);

            // gather h(t+1): 4 u64 agent loads + 2 swizzled ds_write_b128
            {
                const unsigned long long* exq =
                    (const unsigned long long*)&g_ex[(t + 1) & 1][g][0] + tid * 4;
                unsigned long long q0 = __hip_atomic_load(exq + 0, __ATOMIC_RELAXED, __HIP_MEMORY_SCOPE_AGENT);
                unsigned long long q1 = __hip_atomic_load(exq + 1, __ATOMIC_RELAXED, __HIP_MEMORY_SCOPE_AGENT);
                unsigned long long q2 = __hip_atomic_load(exq + 2, __ATOMIC_RELAXED, __HIP_MEMORY_SCOPE_AGENT);
                unsigned long long q3 = __hip_atomic_load(exq + 3, __ATOMIC_RELAXED, __HIP_MEMORY_SCOPE_AGENT);
                const int grow = tid >> 5;
                const int gcb = (tid & 31) * 32;
                const int gsw = (grow & 7) << 4;
                char* hw = (char*)lds_h + grow * 1024;
                union { unsigned long long qq[2]; uint4 v; } c0, c1;
                c0.qq[0] = q0; c0.qq[1] = q1;
                c1.qq[0] = q2; c1.qq[1] = q3;
                *(uint4*)(hw + ((gcb)      ^ gsw)) = c0.v;
                *(uint4*)(hw + ((gcb + 16) ^ gsw)) = c1.v;
            }
            asm volatile("s_waitcnt lgkmcnt(0)" ::: "memory");
            __builtin_amdgcn_s_barrier();
        }

        // hs stores dead-last: retire during the next step, never waited on
        const int tb = (int)t << 9;
        hs[eo0 + tb] = (unsigned short)m00;
        hs[eo1 + tb] = (unsigned short)m01;
        hs[eo2 + tb] = (unsigned short)m02;
        hs[eo3 + tb] = (unsigned short)m03;
    }

    // h_final (fp32) from final-step registers
    float* hfin = out + (size_t)B_ * T_ * O_;
    hfin[(xr + 0) * H_ + n] = bf2f((unsigned short)m00);
    hfin[(xr + 1) * H_ + n] = bf2f((unsigned short)m01);
    hfin[(xr + 2) * H_ + n] = bf2f((unsigned short)m02);
    hfin[(xr + 3) * H_ + n] = bf2f((unsigned short)m03);
}

// ---------------- K3: outputs = hs @ Wd^T + bd, in-place over hs slots ----------------
__launch_bounds__(512, 2)
__global__ void k_out(const float* __restrict__ bd, float* out) {
    int tid = threadIdx.x;
    int w = tid >> 6, l = tid & 63;
    int hi = l >> 4, lo = l & 15;
    size_t m0 = (size_t)blockIdx.x * 256 + w * 32;
    const unsigned short* hsb = (const unsigned short*)out;
    float bdv[16];
#pragma unroll
    for (int nt = 0; nt < 16; nt++) bdv[nt] = bd[nt * 16 + lo];
    f32x4 acc[2][16];
#pragma unroll
    for (int m = 0; m < 2; m++)
#pragma unroll
        for (int nt = 0; nt < 16; nt++) { acc[m][nt][0] = 0.f; acc[m][nt][1] = 0.f; acc[m][nt][2] = 0.f; acc[m][nt][3] = 0.f; }
#pragma unroll 2
    for (int kt = 0; kt < 16; kt++) {
        bf16x8 a0 = *(const bf16x8*)(hsb + (m0 + lo) * 512 + kt * 32 + hi * 8);
        bf16x8 a1 = *(const bf16x8*)(hsb + (m0 + 16 + lo) * 512 + kt * 32 + hi * 8);
#pragma unroll
        for (int nt = 0; nt < 16; nt++) {
            bf16x8 bf = *(const bf16x8*)(g_Wdf + (size_t)(nt * 16 + kt) * 512 + l * 8);
            acc[0][nt] = __builtin_amdgcn_mfma_f32_16x16x32_bf16(a0, bf, acc[0][nt], 0, 0, 0);
            acc[1][nt] = __builtin_amdgcn_mfma_f32_16x16x32_bf16(a1, bf, acc[1][nt], 0, 0, 0);
        }
    }
#pragma unroll
    for (int m = 0; m < 2; m++)
#pragma unroll
        for (int nt = 0; nt < 16; nt++)
#pragma unroll
            for (int rg = 0; rg < 4; rg++) {
                size_t row = m0 + m * 16 + hi * 4 + rg;
                out[row * O_ + nt * 16 + lo] = acc[m][nt][rg] + bdv[nt];
            }
}

extern "C" void kernel_launch(void* const* d_in, const int* in_sizes, int n_in,
                              void* d_out, int out_size, void* d_ws, size_t ws_size,
                              hipStream_t stream) {
    const int*   x   = (const int*)d_in[0];
    const float* h0  = (const float*)d_in[1];
    const float* emb = (const float*)d_in[2];
    const float* W   = (const float*)d_in[3];
    const float* b   = (const float*)d_in[4];
    const float* Wd  = (const float*)d_in[5];
    const float* bd  = (const float*)d_in[6];
    float* out = (float*)d_out;

    k_embWx<<<dim3(V_), dim3(256), 0, stream>>>(emb, W, b);
    k_fragWh<<<dim3(128), dim3(256), 0, stream>>>(W);
    k_fragWd<<<dim3(64), dim3(256), 0, stream>>>(Wd);
    k_rnn<<<dim3(64), dim3(512), 0, stream>>>(x, h0, out);
    k_out<<<dim3(1024), dim3(512), 0, stream>>>(bd, out);
}